// Round 5
// baseline (865.503 us; speedup 1.0000x reference)
//
#include <hip/hip_runtime.h>
#include <math.h>

// total = main_ce + 0.05*rep + 0.2*chord_ce + 0.1*scale_bce
// rep_loss is data-independent: 0.5 * sum_pos min(pos,8) / (S*VOCAB)
// (one-hot rows sum to 1 since ids are always in [0,VOCAB)).
// Single kernel: leaf blocks write partials to ws; the LAST block (device-scope
// fence + atomic counter) reduces them and writes d_out. Counter is zeroed by a
// 4-byte hipMemsetAsync each call (ws is re-poisoned to 0xAA by the harness).

#define VOCAB 2048
#define CHORDV 60

typedef float vf4 __attribute__((ext_vector_type(4)));

__device__ __forceinline__ float waveRedMax(float v) {
#pragma unroll
    for (int off = 32; off > 0; off >>= 1)
        v = fmaxf(v, __shfl_xor(v, off, 64));
    return v;
}

__device__ __forceinline__ float waveRedSum(float v) {
#pragma unroll
    for (int off = 32; off > 0; off >>= 1)
        v += __shfl_xor(v, off, 64);
    return v;
}

__device__ __forceinline__ float bce1(float x, float z) {
    // numerically stable BCE-with-logits; __expf/__logf -> v_exp_f32/v_log_f32
    return fmaxf(x, 0.0f) - x * z + __logf(1.0f + __expf(-fabsf(x)));
}

__device__ __forceinline__ float blockSum256(float v, float* red) {
    const int lane = threadIdx.x & 63;
    const int wave = threadIdx.x >> 6;
    float w = waveRedSum(v);
    __syncthreads();  // guard red reuse across calls
    if (lane == 0) red[wave] = w;
    __syncthreads();
    return red[0] + red[1] + red[2] + red[3];
}

// blocks [0, BS): main CE, one row of 2048 per block (256 thr, 8 floats/thr)
// blocks [BS, BS+chordBlocks): chord CE, 4 rows of 60 per block (1/wave), pre-reduced
// blocks [BS+chordBlocks, +scaleBlocks): scale BCE, 1024 elems per block
__global__ __launch_bounds__(256) void fused_loss_kernel(
    const float* __restrict__ logits, const int* __restrict__ tgt,
    const float* __restrict__ chordL, const int* __restrict__ chordT,
    const float* __restrict__ sx, const float* __restrict__ sz,
    float2* __restrict__ mainNV, float2* __restrict__ chordNV,
    float* __restrict__ scaleP, unsigned int* __restrict__ counter,
    float* __restrict__ out,
    int BS, int chordBlocks, int scaleBlocks, int n4, int S, int scaleN) {
    const int bid = blockIdx.x;
    const int tid = threadIdx.x;
    const int lane = tid & 63;
    const int wave = tid >> 6;
    const int totalBlocks = BS + chordBlocks + scaleBlocks;

    __shared__ float red[4];
    __shared__ float xt_sh;
    __shared__ float2 csh[4];
    __shared__ bool amLast;

    if (bid < BS) {
        // ---- main CE row ----
        const int row = bid;
        const int t = tgt[row];  // issued first: latency overlaps the row stream
        const float* p = logits + (size_t)row * VOCAB;

        vf4 a = __builtin_nontemporal_load(((const vf4*)p) + tid);
        vf4 b = __builtin_nontemporal_load(((const vf4*)p) + tid + 256);

        const bool valid = (t >= 0) && (t < VOCAB);
        if (valid) {
            const int owner = t >> 2;
            const int comp = t & 3;
            if (owner == tid) xt_sh = a[comp];
            else if (owner == tid + 256) xt_sh = b[comp];
        }

        float m = fmaxf(fmaxf(fmaxf(a[0], a[1]), fmaxf(a[2], a[3])),
                        fmaxf(fmaxf(b[0], b[1]), fmaxf(b[2], b[3])));
        float wm = waveRedMax(m);
        if (lane == 0) red[wave] = wm;
        __syncthreads();
        const float bm = fmaxf(fmaxf(red[0], red[1]), fmaxf(red[2], red[3]));
        __syncthreads();  // red reused

        float s = __expf(a[0] - bm) + __expf(a[1] - bm) + __expf(a[2] - bm) + __expf(a[3] - bm)
                + __expf(b[0] - bm) + __expf(b[1] - bm) + __expf(b[2] - bm) + __expf(b[3] - bm);
        float ws_ = waveRedSum(s);
        if (lane == 0) red[wave] = ws_;
        __syncthreads();

        if (tid == 0) {
            const float bs = red[0] + red[1] + red[2] + red[3];
            float2 nv = make_float2(0.0f, 0.0f);
            if (valid) {
                nv.x = -(xt_sh - bm - __logf(bs));
                nv.y = 1.0f;
            }
            mainNV[row] = nv;
        }
    } else if (bid < BS + chordBlocks) {
        // ---- chord CE: 4 rows, one per wave, pre-reduced to one float2 ----
        const int cb = bid - BS;
        const int row = cb * 4 + wave;
        float2 nv = make_float2(0.0f, 0.0f);
        if (row < BS) {
            const float* p = chordL + (size_t)row * CHORDV;
            const int t = chordT[row];
            float x = (lane < CHORDV) ? p[lane] : -INFINITY;
            float m = waveRedMax(x);
            float e = (lane < CHORDV) ? __expf(x - m) : 0.0f;
            float s = waveRedSum(e);
            if (t != -1000000000) {  // ignore_index = -(10**9)
                nv.x = -(p[t] - m - __logf(s));
                nv.y = 1.0f;
            }
        }
        if (lane == 0) csh[wave] = nv;
        __syncthreads();
        if (tid == 0) {
            chordNV[cb] = make_float2(csh[0].x + csh[1].x + csh[2].x + csh[3].x,
                                      csh[0].y + csh[1].y + csh[2].y + csh[3].y);
        }
    } else {
        // ---- scale BCE ----
        const int sb = bid - BS - chordBlocks;
        const int i = sb * 256 + tid;
        float s = 0.0f;
        if (i < n4) {
            float4 xv = ((const float4*)sx)[i];
            float4 zv = ((const float4*)sz)[i];
            s = bce1(xv.x, zv.x) + bce1(xv.y, zv.y) + bce1(xv.z, zv.z) + bce1(xv.w, zv.w);
        }
        float wsum = waveRedSum(s);
        if (lane == 0) red[wave] = wsum;
        __syncthreads();
        if (tid == 0) scaleP[sb] = red[0] + red[1] + red[2] + red[3];
    }

    // ---- last-block finalize (device-scope fence + counter) ----
    __threadfence();  // release: partial stores visible before counter bump
    if (tid == 0) {
        unsigned int old = atomicAdd(counter, 1u);  // device-scope by default
        amLast = (old == (unsigned int)(totalBlocks - 1));
    }
    __syncthreads();  // amLast is block-uniform after this
    if (!amLast) return;
    __threadfence();  // acquire: all other blocks' partials now visible

    float sm = 0.f, svm = 0.f, sc = 0.f, svc = 0.f, ss = 0.f;
    const float4* m4 = (const float4*)mainNV;  // (nll,valid) pairs, 2 rows/float4
    for (int i = tid; i < BS / 2; i += 256) {
        float4 v = m4[i];
        sm += v.x + v.z;
        svm += v.y + v.w;
    }
    if ((BS & 1) && tid == 0) { float2 v = mainNV[BS - 1]; sm += v.x; svm += v.y; }

    const float4* c4 = (const float4*)chordNV;
    for (int i = tid; i < chordBlocks / 2; i += 256) {
        float4 v = c4[i];
        sc += v.x + v.z;
        svc += v.y + v.w;
    }
    if ((chordBlocks & 1) && tid == 0) { float2 v = chordNV[chordBlocks - 1]; sc += v.x; svc += v.y; }

    for (int i = tid; i < scaleBlocks; i += 256) ss += scaleP[i];

    __syncthreads();  // red[] was used by the leaf phase
    sm  = blockSum256(sm,  red);
    svm = blockSum256(svm, red);
    sc  = blockSum256(sc,  red);
    svc = blockSum256(svc, red);
    ss  = blockSum256(ss,  red);

    if (tid == 0) {
        const float main_loss  = sm / fmaxf(svm, 1.0f);
        const float chord_loss = sc / fmaxf(svc, 1.0f);
        const float scale_loss = ss / (float)scaleN;
        double wsum = (S >= 8) ? (28.0 + 8.0 * (double)(S - 8))
                               : ((double)S * (double)(S - 1) * 0.5);
        const float rep_loss = (float)(0.5 * wsum / ((double)S * (double)VOCAB));
        out[0] = main_loss + 0.05f * rep_loss + 0.2f * chord_loss + 0.1f * scale_loss;
    }
}

extern "C" void kernel_launch(void* const* d_in, const int* in_sizes, int n_in,
                              void* d_out, int out_size, void* d_ws, size_t ws_size,
                              hipStream_t stream) {
    const float* logits        = (const float*)d_in[0];  // [B,S,2048]
    const float* chord_logits  = (const float*)d_in[1];  // [B,S,60]
    const float* scale_logits  = (const float*)d_in[2];  // [B,S,12]
    const float* scale_targets = (const float*)d_in[3];  // [B,S,12]
    const int*   target_ids    = (const int*)d_in[4];    // [B,S]
    // d_in[5] = key_ids [B] — unused by the reference
    const int*   chord_targets = (const int*)d_in[6];    // [B,S]

    const int BS = in_sizes[4];       // B*S = 8192
    const int B  = in_sizes[5];
    const int S  = BS / B;
    const int scaleN = in_sizes[2];   // B*S*12
    const int n4 = scaleN / 4;
    const int scaleBlocks = (n4 + 255) / 256;   // 96
    const int chordBlocks = (BS + 3) / 4;       // 2048

    // ws layout: [0,BS) float2 main | [BS,BS+chordBlocks) float2 chord |
    // scaleBlocks floats | (256B-aligned) unsigned counter.
    float2* mainNV  = (float2*)d_ws;
    float2* chordNV = mainNV + BS;
    float*  scaleP  = (float*)(chordNV + chordBlocks);
    size_t usedFloats = (size_t)2 * BS + (size_t)2 * chordBlocks + scaleBlocks;
    usedFloats = (usedFloats + 63) & ~(size_t)63;  // 256 B align: keep counter off partial lines
    unsigned int* counter = (unsigned int*)((float*)d_ws + usedFloats);

    hipMemsetAsync(counter, 0, sizeof(unsigned int), stream);

    const int totalBlocks = BS + chordBlocks + scaleBlocks;
    fused_loss_kernel<<<totalBlocks, 256, 0, stream>>>(
        logits, target_ids, chord_logits, chord_targets,
        scale_logits, scale_targets, mainNV, chordNV, scaleP,
        counter, (float*)d_out,
        BS, chordBlocks, scaleBlocks, n4, S, scaleN);
}

// Round 6
// 113.760 us; speedup vs baseline: 7.6081x; 7.6081x over previous
//
#include <hip/hip_runtime.h>
#include <math.h>

// total = main_ce + 0.05*rep + 0.2*chord_ce + 0.1*scale_bce
// rep_loss is data-independent: 0.5 * sum_pos min(pos,8) / (S*VOCAB)
// (one-hot rows sum to 1 since ids are always in [0,VOCAB)).
//
// Two-kernel structure is deliberate (measured): fusing the finalize into the
// leaf kernel via last-block + __threadfence() costs ~77 ns/block of L2
// writeback on multi-XCD gfx950 (R5: 799 us kernel). The kernel-launch
// boundary IS the cheap device-scope fence.

#define VOCAB 2048
#define CHORDV 60

// native vector type: required by __builtin_nontemporal_load (HIP float4 is a struct)
typedef float vf4 __attribute__((ext_vector_type(4)));

__device__ __forceinline__ float waveRedMax(float v) {
#pragma unroll
    for (int off = 32; off > 0; off >>= 1)
        v = fmaxf(v, __shfl_xor(v, off, 64));
    return v;
}

__device__ __forceinline__ float waveRedSum(float v) {
#pragma unroll
    for (int off = 32; off > 0; off >>= 1)
        v += __shfl_xor(v, off, 64);
    return v;
}

__device__ __forceinline__ float bce1(float x, float z) {
    // numerically stable BCE-with-logits; __expf/__logf -> v_exp_f32/v_log_f32
    return fmaxf(x, 0.0f) - x * z + __logf(1.0f + __expf(-fabsf(x)));
}

// ---------------- fused leaf kernel ----------------
// blocks [0, BS): main CE, one row of 2048 per block
// blocks [BS, BS+chordBlocks): chord CE, 4 rows of 60 per block (1/wave), pre-reduced
// blocks [BS+chordBlocks, ...): scale BCE, 1024 elems per block
__global__ __launch_bounds__(256) void fused_leaf_kernel(
    const float* __restrict__ logits, const int* __restrict__ tgt,
    const float* __restrict__ chordL, const int* __restrict__ chordT,
    const float* __restrict__ sx, const float* __restrict__ sz,
    float2* __restrict__ mainNV, float2* __restrict__ chordNV,
    float* __restrict__ scaleP, int BS, int chordBlocks, int n4) {
    const int bid = blockIdx.x;
    const int tid = threadIdx.x;
    const int lane = tid & 63;
    const int wave = tid >> 6;

    __shared__ float red[4];
    __shared__ float xt_sh;
    __shared__ float2 csh[4];

    if (bid < BS) {
        // ---- main CE row ----
        const int row = bid;
        const int t = tgt[row];  // issued first: latency overlaps the row stream
        const float* p = logits + (size_t)row * VOCAB;

        // 8 floats/thread, 16B/lane, read-once stream -> nontemporal
        vf4 a = __builtin_nontemporal_load(((const vf4*)p) + tid);
        vf4 b = __builtin_nontemporal_load(((const vf4*)p) + tid + 256);

        // target logit from the owning thread's registers (no global reload)
        const bool valid = (t >= 0) && (t < VOCAB);
        if (valid) {
            const int owner = t >> 2;          // vf4 index owning element t
            const int comp = t & 3;
            if (owner == tid) {
                xt_sh = a[comp];
            } else if (owner == tid + 256) {
                xt_sh = b[comp];
            }
        }

        float m = fmaxf(fmaxf(fmaxf(a[0], a[1]), fmaxf(a[2], a[3])),
                        fmaxf(fmaxf(b[0], b[1]), fmaxf(b[2], b[3])));
        float wm = waveRedMax(m);
        if (lane == 0) red[wave] = wm;
        __syncthreads();
        const float bm = fmaxf(fmaxf(red[0], red[1]), fmaxf(red[2], red[3]));
        __syncthreads();  // red reused

        float s = __expf(a[0] - bm) + __expf(a[1] - bm) + __expf(a[2] - bm) + __expf(a[3] - bm)
                + __expf(b[0] - bm) + __expf(b[1] - bm) + __expf(b[2] - bm) + __expf(b[3] - bm);
        float ws_ = waveRedSum(s);
        if (lane == 0) red[wave] = ws_;
        __syncthreads();

        if (tid == 0) {
            const float bs = red[0] + red[1] + red[2] + red[3];
            float2 nv = make_float2(0.0f, 0.0f);
            if (valid) {
                nv.x = -(xt_sh - bm - __logf(bs));
                nv.y = 1.0f;
            }
            mainNV[row] = nv;
        }
    } else if (bid < BS + chordBlocks) {
        // ---- chord CE: 4 rows, one per wave, pre-reduced to one float2 ----
        const int cb = bid - BS;
        const int row = cb * 4 + wave;
        float2 nv = make_float2(0.0f, 0.0f);
        if (row < BS) {
            const float* p = chordL + (size_t)row * CHORDV;
            const int t = chordT[row];
            float x = (lane < CHORDV) ? p[lane] : -INFINITY;
            float m = waveRedMax(x);
            float e = (lane < CHORDV) ? __expf(x - m) : 0.0f;
            float s = waveRedSum(e);
            if (t != -1000000000) {  // ignore_index = -(10**9), never hit here
                nv.x = -(p[t] - m - __logf(s));
                nv.y = 1.0f;
            }
        }
        if (lane == 0) csh[wave] = nv;
        __syncthreads();
        if (tid == 0) {
            chordNV[cb] = make_float2(csh[0].x + csh[1].x + csh[2].x + csh[3].x,
                                      csh[0].y + csh[1].y + csh[2].y + csh[3].y);
        }
    } else {
        // ---- scale BCE ----
        const int sb = bid - BS - chordBlocks;
        const int i = sb * 256 + tid;
        float s = 0.0f;
        if (i < n4) {
            float4 xv = ((const float4*)sx)[i];
            float4 zv = ((const float4*)sz)[i];
            s = bce1(xv.x, zv.x) + bce1(xv.y, zv.y) + bce1(xv.z, zv.z) + bce1(xv.w, zv.w);
        }
        float wsum = waveRedSum(s);
        if (lane == 0) red[wave] = wsum;
        __syncthreads();
        if (tid == 0) scaleP[sb] = red[0] + red[1] + red[2] + red[3];
    }
}

// ---------------- finalize: 1 block x 1024 threads ----------------
__device__ __forceinline__ float blockSum1024(float v, float* red16) {
    const int lane = threadIdx.x & 63;
    const int wave = threadIdx.x >> 6;
    float w = waveRedSum(v);
    __syncthreads();  // guard reuse across calls
    if (lane == 0) red16[wave] = w;
    __syncthreads();
    float r = 0.0f;
#pragma unroll
    for (int k = 0; k < 16; ++k) r += red16[k];  // LDS broadcast, conflict-free
    return r;
}

__global__ __launch_bounds__(1024) void finalize_kernel(
    const float2* __restrict__ mainNV, const float2* __restrict__ chordNV,
    const float* __restrict__ scaleP, int BS, int chordBlocks, int nScaleBlocks,
    int S, int scaleN, float* __restrict__ out) {
    const int tid = threadIdx.x;
    float sm = 0.f, svm = 0.f, sc = 0.f, svc = 0.f, ss = 0.f;

    const float4* m4 = (const float4*)mainNV;  // (nll,valid) pairs, float4 = 2 rows
    for (int i = tid; i < BS / 2; i += 1024) {
        float4 v = m4[i];
        sm += v.x + v.z;
        svm += v.y + v.w;
    }
    if ((BS & 1) && tid == 0) { float2 v = mainNV[BS - 1]; sm += v.x; svm += v.y; }

    const float4* c4 = (const float4*)chordNV;
    for (int i = tid; i < chordBlocks / 2; i += 1024) {
        float4 v = c4[i];
        sc += v.x + v.z;
        svc += v.y + v.w;
    }
    if ((chordBlocks & 1) && tid == 0) { float2 v = chordNV[chordBlocks - 1]; sc += v.x; svc += v.y; }

    for (int i = tid; i < nScaleBlocks; i += 1024) ss += scaleP[i];

    __shared__ float red16[16];
    sm  = blockSum1024(sm,  red16);
    svm = blockSum1024(svm, red16);
    sc  = blockSum1024(sc,  red16);
    svc = blockSum1024(svc, red16);
    ss  = blockSum1024(ss,  red16);

    if (tid == 0) {
        const float main_loss  = sm / fmaxf(svm, 1.0f);
        const float chord_loss = sc / fmaxf(svc, 1.0f);
        const float scale_loss = ss / (float)scaleN;
        // rep_loss: data-independent constant (header comment)
        double wsum = (S >= 8) ? (28.0 + 8.0 * (double)(S - 8))
                               : ((double)S * (double)(S - 1) * 0.5);
        const float rep_loss = (float)(0.5 * wsum / ((double)S * (double)VOCAB));
        out[0] = main_loss + 0.05f * rep_loss + 0.2f * chord_loss + 0.1f * scale_loss;
    }
}

extern "C" void kernel_launch(void* const* d_in, const int* in_sizes, int n_in,
                              void* d_out, int out_size, void* d_ws, size_t ws_size,
                              hipStream_t stream) {
    const float* logits        = (const float*)d_in[0];  // [B,S,2048]
    const float* chord_logits  = (const float*)d_in[1];  // [B,S,60]
    const float* scale_logits  = (const float*)d_in[2];  // [B,S,12]
    const float* scale_targets = (const float*)d_in[3];  // [B,S,12]
    const int*   target_ids    = (const int*)d_in[4];    // [B,S]
    // d_in[5] = key_ids [B] — unused by the reference
    const int*   chord_targets = (const int*)d_in[6];    // [B,S]

    const int BS = in_sizes[4];       // B*S = 8192
    const int B  = in_sizes[5];
    const int S  = BS / B;
    const int scaleN = in_sizes[2];   // B*S*12 (divisible by 4)
    const int n4 = scaleN / 4;
    const int nScaleBlocks = (n4 + 255) / 256;
    const int chordBlocks = (BS + 3) / 4;

    // ws layout (all written every call before being read — poison-safe):
    // [0, BS) float2 main (nll,valid) | [BS, BS+chordBlocks) float2 chord
    // then nScaleBlocks floats of scale partials
    float2* mainNV  = (float2*)d_ws;
    float2* chordNV = mainNV + BS;
    float*  scaleP  = (float*)(chordNV + chordBlocks);

    const int totalBlocks = BS + chordBlocks + nScaleBlocks;
    fused_leaf_kernel<<<totalBlocks, 256, 0, stream>>>(
        logits, target_ids, chord_logits, chord_targets,
        scale_logits, scale_targets, mainNV, chordNV, scaleP,
        BS, chordBlocks, n4);
    finalize_kernel<<<1, 1024, 0, stream>>>(mainNV, chordNV, scaleP,
                                            BS, chordBlocks, nScaleBlocks,
                                            S, scaleN, (float*)d_out);
}